// Round 2
// baseline (286.865 us; speedup 1.0000x reference)
//
#include <hip/hip_runtime.h>
#include <hip/hip_bf16.h>
#include <hip/hip_fp16.h>

typedef unsigned short u16;
typedef unsigned int u32;
typedef __bf16 bf16x8 __attribute__((ext_vector_type(8)));
typedef float f32x4 __attribute__((ext_vector_type(4)));
typedef u16 u16x8 __attribute__((ext_vector_type(8)));

// N_NODES=131072, IN_CHANNELS=256, NUM_PROJ=256, NUM_QUANT=256, NUM_GRAPHS=256
// nodes_per_graph = 512; scale = sqrt(256*256) = 256.

__device__ __forceinline__ u16 f2bf(float f) {
  union { float f; u32 u; } v; v.f = f;
  u32 r = (v.u + 0x7FFFu + ((v.u >> 16) & 1u)) >> 16;  // RNE
  return (u16)r;
}

// pack two fp32 -> packed bf16 pair (a low, b high), RNE — single VOP3
// (v_cvt_pk_bf16_f32 has no builtin on gfx950; inline asm per T12 recipe)
__device__ __forceinline__ u32 cvtpk(float a, float b) {
  u32 r; asm("v_cvt_pk_bf16_f32 %0, %1, %2" : "=v"(r) : "v"(a), "v"(b));
  return r;
}

// async global->LDS, 16B per lane; lds base wave-uniform, scatter = +lane*16
__device__ __forceinline__ void gl16(const void* g, void* l) {
  __builtin_amdgcn_global_load_lds((const __attribute__((address_space(1))) unsigned int*)g,
                                   (__attribute__((address_space(3))) unsigned int*)l,
                                   16, 0, 0);
}

// packed fp16 min/max (1 VOP3P each, both halves)
__device__ __forceinline__ u32 pkmin(u32 a, u32 b) {
  u32 r; asm("v_pk_min_f16 %0, %1, %2" : "=v"(r) : "v"(a), "v"(b)); return r;
}
__device__ __forceinline__ u32 pkmax(u32 a, u32 b) {
  u32 r; asm("v_pk_max_f16 %0, %1, %2" : "=v"(r) : "v"(a), "v"(b)); return r;
}

// cross-lane exchange: DPP (VALU pipe, free of DS) / ds_swizzle / bpermute
template <int CTRL> __device__ __forceinline__ u32 xdpp(u32 x) {
  return (u32)__builtin_amdgcn_mov_dpp((int)x, CTRL, 0xF, 0xF, true);
}
template <int IMM> __device__ __forceinline__ u32 xswz(u32 x) {
  return (u32)__builtin_amdgcn_ds_swizzle((int)x, IMM);
}
#define EX_X1(x)  xdpp<0xB1>(x)      /* quad_perm [1,0,3,2]  = xor 1  */
#define EX_X2(x)  xdpp<0x4E>(x)      /* quad_perm [2,3,0,1]  = xor 2  */
#define EX_F3(x)  xdpp<0x1B>(x)      /* quad_perm [3,2,1,0]  = xor 3  */
#define EX_F7(x)  xdpp<0x141>(x)     /* half_mirror          = xor 7  */
#define EX_F15(x) xdpp<0x140>(x)     /* row_mirror           = xor 15 */
#define EX_X8(x)  xdpp<0x128>(x)     /* row_ror:8            = xor 8  */
#define EX_X4(x)  xswz<0x101F>(x)    /* swizzle xor 4  */
#define EX_X16(x) xswz<0x401F>(x)    /* swizzle xor 16 */
#define EX_F31(x) xswz<0x7C1F>(x)    /* swizzle xor 31 */
#define EX_F63(x) ((u32)__shfl_xor((int)(x), 63, 64))

// ---------------- Kernel 0: proj (k-major fp32) -> projT[p][k] bf16 ----------------
__global__ __launch_bounds__(256) void transpose_proj(const float* __restrict__ proj,
                                                      u16* __restrict__ projT) {
  const int k = blockIdx.x;
  const int p = threadIdx.x;
  projT[(size_t)p * 256 + k] = f2bf(proj[(size_t)k * 256 + p]);
}

// ---------------- Kernel 1: xp16[p][n] = fp16(sum_k proj[k][p] * x[n][k]) -----------
__global__ __launch_bounds__(256) void gemm_xt(const float* __restrict__ x,
                                               const u16* __restrict__ projT,
                                               __half* __restrict__ xp16) {
  __shared__ u16 As[128 * 32];    // As[p][k] bf16
  __shared__ float Bs[128 * 32];  // Bs[n][k] fp32

  const int tid = threadIdx.x;
  const int bid = blockIdx.x;
  // XCD-aware swizzle: blocks b and b+8 share the same x n-tile and land on the
  // same XCD (bid%8) -> second block L2-hits the tile instead of refetching HBM.
  const int slot = bid & 7;
  const int j = bid >> 3;
  const int p0 = (j & 1) * 128;
  const int n0 = (slot + (j >> 1) * 8) * 128;
  const int lane = tid & 63;
  const int w = tid >> 6;
  const int wp = (w >> 1) * 64;
  const int wn = (w & 1) * 64;
  const int quad = lane >> 4;
  const int m16 = lane & 15;

  const u16* asrc0 = projT + (size_t)(p0 + (2 * w) * 16 + (lane >> 2)) * 256 + (lane & 3) * 8;
  const u16* asrc1 = asrc0 + 16 * 256;
  u16* adst0 = &As[(2 * w) * 512];
  u16* adst1 = &As[(2 * w + 1) * 512];
  const float* bsrc0 = x + (size_t)(n0 + (4 * w) * 8 + (lane >> 3)) * 256 + (lane & 7) * 4;
  const float* bsrc1 = bsrc0 + 8 * 256;
  const float* bsrc2 = bsrc0 + 16 * 256;
  const float* bsrc3 = bsrc0 + 24 * 256;
  float* bdst0 = &Bs[(4 * w) * 256];
  float* bdst1 = &Bs[(4 * w + 1) * 256];
  float* bdst2 = &Bs[(4 * w + 2) * 256];
  float* bdst3 = &Bs[(4 * w + 3) * 256];

  f32x4 acc[4][4];
#pragma unroll
  for (int i = 0; i < 4; ++i)
#pragma unroll
    for (int jj = 0; jj < 4; ++jj) acc[i][jj] = (f32x4){0.f, 0.f, 0.f, 0.f};

  for (int k0 = 0; k0 < 256; k0 += 32) {
    gl16(bsrc0 + k0, bdst0);
    gl16(bsrc1 + k0, bdst1);
    gl16(bsrc2 + k0, bdst2);
    gl16(bsrc3 + k0, bdst3);
    gl16(asrc0 + k0, adst0);
    gl16(asrc1 + k0, adst1);
    __syncthreads();

    bf16x8 af[4], bfv[4];
#pragma unroll
    for (int mi = 0; mi < 4; ++mi)
      af[mi] = *(const bf16x8*)&As[(wp + mi * 16 + m16) * 32 + quad * 8];
#pragma unroll
    for (int ni = 0; ni < 4; ++ni) {
      const float* bp = &Bs[(wn + ni * 16 + m16) * 32 + quad * 8];
      float4 f0 = *(const float4*)bp;
      float4 f1 = *(const float4*)(bp + 4);
      // v_cvt_pk_bf16_f32: 1 VOP3 per fp32 pair (was ~6 VALU ops via pk_rne bit math)
      u32 pk[4] = { cvtpk(f0.x, f0.y), cvtpk(f0.z, f0.w),
                    cvtpk(f1.x, f1.y), cvtpk(f1.z, f1.w) };
      bfv[ni] = *(const bf16x8*)pk;
    }
#pragma unroll
    for (int mi = 0; mi < 4; ++mi)
#pragma unroll
      for (int ni = 0; ni < 4; ++ni)
        acc[mi][ni] = __builtin_amdgcn_mfma_f32_16x16x32_bf16(af[mi], bfv[ni], acc[mi][ni], 0, 0, 0);
    __syncthreads();
  }

  // epilogue: D row = m = quad*4 + reg, col = n = m16  -> xp16[p][n]
#pragma unroll
  for (int mi = 0; mi < 4; ++mi) {
#pragma unroll
    for (int r = 0; r < 4; ++r) {
      const int p = p0 + wp + mi * 16 + quad * 4 + r;
      __half* dst = xp16 + (size_t)p * 131072 + (n0 + wn + m16);
#pragma unroll
      for (int ni = 0; ni < 4; ++ni) dst[ni * 16] = __float2half(acc[mi][ni][r]);
    }
  }
}

// ---------------- Kernel 2: packed dual-group sort of 512 + quantile select --------
// Each wave sorts TWO groups at once: u32 reg = fp16 pair (lo = p, hi = p+16),
// compare-exchange via v_pk_min/max_f16. Cross-lane XOR 1/2/3/7/8/15 ride the VALU
// pipe as DPP; only XOR 4/16/31/63 touch the DS pipe (48 DS ops/wave vs 168).
__global__ __launch_bounds__(1024) void sort_sel(const __half* __restrict__ xp16,
                                                 const float* __restrict__ cw,
                                                 float* __restrict__ out) {
  __shared__ u32 sbuf[16][520];  // 520: 16B-aligned rows
  const int tid = threadIdx.x;
  const int lane = tid & 63;
  const int w = tid >> 6;
  const int bid = blockIdx.x;
  const int g = bid >> 3;
  const int pt = bid & 7;
  const int p_lo = pt * 32 + w;
  const int p_hi = p_lo + 16;

  const u16* slo = (const u16*)(xp16 + (size_t)p_lo * 131072 + (size_t)g * 512) + lane * 8;
  const u16* shi = (const u16*)(xp16 + (size_t)p_hi * 131072 + (size_t)g * 512) + lane * 8;
  u16x8 lo = *(const u16x8*)slo;
  u16x8 hi = *(const u16x8*)shi;
  u32 v[8];
#pragma unroll
  for (int r = 0; r < 8; ++r) v[r] = (u32)lo[r] | ((u32)hi[r] << 16);

#define CE(i, j) { u32 mn_ = pkmin(v[i], v[j]); u32 mx_ = pkmax(v[i], v[j]); v[i] = mn_; v[j] = mx_; }
#define INTRA3 \
  CE(0,4) CE(1,5) CE(2,6) CE(3,7) \
  CE(0,2) CE(1,3) CE(4,6) CE(5,7) \
  CE(0,1) CE(2,3) CE(4,5) CE(6,7)

#define FLIPP(EX, lowbit) { \
    const bool low_ = (lane & (lowbit)) == 0; \
    u32 t_[8]; \
    _Pragma("unroll") for (int r = 0; r < 8; ++r) t_[r] = EX(v[7 - r]); \
    _Pragma("unroll") for (int r = 0; r < 8; ++r) { \
      u32 mn_ = pkmin(v[r], t_[r]); u32 mx_ = pkmax(v[r], t_[r]); \
      v[r] = low_ ? mn_ : mx_; } }

#define XCROSSP(EX, lm) { \
    const bool low_ = (lane & (lm)) == 0; \
    _Pragma("unroll") for (int r = 0; r < 8; ++r) { \
      u32 t_ = EX(v[r]); \
      u32 mn_ = pkmin(v[r], t_); u32 mx_ = pkmax(v[r], t_); \
      v[r] = low_ ? mn_ : mx_; } }

  // S=2
  CE(0,1) CE(2,3) CE(4,5) CE(6,7)
  // S=4
  CE(0,3) CE(1,2) CE(4,7) CE(5,6)
  CE(0,1) CE(2,3) CE(4,5) CE(6,7)
  // S=8
  CE(0,7) CE(1,6) CE(2,5) CE(3,4)
  CE(0,2) CE(1,3) CE(4,6) CE(5,7)
  CE(0,1) CE(2,3) CE(4,5) CE(6,7)
  // S=16
  FLIPP(EX_X1, 1)  INTRA3
  // S=32
  FLIPP(EX_F3, 2)  XCROSSP(EX_X1, 1)  INTRA3
  // S=64
  FLIPP(EX_F7, 4)  XCROSSP(EX_X2, 2) XCROSSP(EX_X1, 1)  INTRA3
  // S=128
  FLIPP(EX_F15, 8) XCROSSP(EX_X4, 4) XCROSSP(EX_X2, 2) XCROSSP(EX_X1, 1)  INTRA3
  // S=256
  FLIPP(EX_F31, 16) XCROSSP(EX_X8, 8) XCROSSP(EX_X4, 4) XCROSSP(EX_X2, 2) XCROSSP(EX_X1, 1)  INTRA3
  // S=512
  FLIPP(EX_F63, 32) XCROSSP(EX_X16, 16) XCROSSP(EX_X8, 8) XCROSSP(EX_X4, 4) XCROSSP(EX_X2, 2) XCROSSP(EX_X1, 1)  INTRA3

#undef CE
#undef INTRA3
#undef FLIPP
#undef XCROSSP

  // park both sorted groups (packed) in LDS
  *(uint4*)&sbuf[w][lane * 8]     = (uint4){v[0], v[1], v[2], v[3]};
  *(uint4*)&sbuf[w][lane * 8 + 4] = (uint4){v[4], v[5], v[6], v[7]};
  __syncthreads();

  // selection: out[g][q][pt*32+pl] = sorted[idx[q]] / 256
  const float scale = 1.0f / 256.0f;
#pragma unroll
  for (int it = 0; it < 8; ++it) {
    const int linear = it * 1024 + tid;  // 0..8191
    const int q = linear >> 5;
    const int pl = linear & 31;
    const int iq = (int)floorf(cw[q] * 511.0f);
    const u32 val = sbuf[pl & 15][iq];
    const u16 h = (pl & 16) ? (u16)(val >> 16) : (u16)(val & 0xFFFF);
    __half_raw hr; hr.x = h;
    out[(size_t)g * 65536 + (size_t)q * 256 + pt * 32 + pl] = __half2float(__half(hr)) * scale;
  }
}

extern "C" void kernel_launch(void* const* d_in, const int* in_sizes, int n_in,
                              void* d_out, int out_size, void* d_ws, size_t ws_size,
                              hipStream_t stream) {
  const float* x    = (const float*)d_in[0];  // (131072, 256) fp32
  const float* proj = (const float*)d_in[1];  // (256, 256) fp32
  const float* cw   = (const float*)d_in[2];  // (256,) fp32
  float* out = (float*)d_out;                 // (256, 65536) fp32

  __half* xp16 = (__half*)d_ws;                                 // 64 MiB: xp16[256][131072]
  u16* projT = (u16*)((char*)d_ws + (size_t)64 * 1024 * 1024);  // 128 KiB

  transpose_proj<<<256, 256, 0, stream>>>(proj, projT);
  gemm_xt<<<2048, 256, 0, stream>>>(x, projT, xp16);
  sort_sel<<<2048, 1024, 0, stream>>>(xp16, cw, out);
}

// Round 5
// 284.348 us; speedup vs baseline: 1.0089x; 1.0089x over previous
//
#include <hip/hip_runtime.h>
#include <hip/hip_fp16.h>

typedef unsigned short u16;
typedef unsigned int u32;
typedef __bf16 bf16x8 __attribute__((ext_vector_type(8)));
typedef float f32x4 __attribute__((ext_vector_type(4)));

// N_NODES=131072, IN_CHANNELS=256, NUM_PROJ=256, NUM_QUANT=256, NUM_GRAPHS=256
// nodes_per_graph = 512; scale = sqrt(256*256) = 256.

__device__ __forceinline__ u16 f2bf(float f) {
  union { float f; u32 u; } v; v.f = f;
  u32 r = (v.u + 0x7FFFu + ((v.u >> 16) & 1u)) >> 16;  // RNE
  return (u16)r;
}

// pack two fp32 -> packed bf16 pair (a low, b high), RNE — single VOP3
__device__ __forceinline__ u32 cvtpk(float a, float b) {
  u32 r; asm("v_cvt_pk_bf16_f32 %0, %1, %2" : "=v"(r) : "v"(a), "v"(b));
  return r;
}

// pack two fp32 -> packed fp16 pair, RNE (matches __float2half semantics)
__device__ __forceinline__ u32 pkh(float a, float b) {
  return (u32)__half_as_ushort(__float2half(a)) |
         ((u32)__half_as_ushort(__float2half(b)) << 16);
}

// v_perm_b32: sel byte<4 -> S1 bytes, >=4 -> S0 bytes
__device__ __forceinline__ u32 vperm(u32 s0, u32 s1, u32 sel) {
  u32 r; asm("v_perm_b32 %0, %1, %2, %3" : "=v"(r) : "v"(s0), "v"(s1), "s"(sel));
  return r;
}

// packed fp16 min/max (1 VOP3P each, both halves)
__device__ __forceinline__ u32 pkmin(u32 a, u32 b) {
  u32 r; asm("v_pk_min_f16 %0, %1, %2" : "=v"(r) : "v"(a), "v"(b)); return r;
}
__device__ __forceinline__ u32 pkmax(u32 a, u32 b) {
  u32 r; asm("v_pk_max_f16 %0, %1, %2" : "=v"(r) : "v"(a), "v"(b)); return r;
}

// cross-lane exchange: DPP (VALU pipe, free of DS) / ds_swizzle / bpermute
template <int CTRL> __device__ __forceinline__ u32 xdpp(u32 x) {
  return (u32)__builtin_amdgcn_mov_dpp((int)x, CTRL, 0xF, 0xF, true);
}
template <int IMM> __device__ __forceinline__ u32 xswz(u32 x) {
  return (u32)__builtin_amdgcn_ds_swizzle((int)x, IMM);
}
#define EX_X1(x)  xdpp<0xB1>(x)      /* quad_perm [1,0,3,2]  = xor 1  */
#define EX_X2(x)  xdpp<0x4E>(x)      /* quad_perm [2,3,0,1]  = xor 2  */
#define EX_F3(x)  xdpp<0x1B>(x)      /* quad_perm [3,2,1,0]  = xor 3  */
#define EX_F7(x)  xdpp<0x141>(x)     /* half_mirror          = xor 7  */
#define EX_F15(x) xdpp<0x140>(x)     /* row_mirror           = xor 15 */
#define EX_X8(x)  xdpp<0x128>(x)     /* row_ror:8            = xor 8  */
#define EX_X4(x)  xswz<0x101F>(x)    /* swizzle xor 4  */
#define EX_X16(x) xswz<0x401F>(x)    /* swizzle xor 16 */
#define EX_F31(x) xswz<0x7C1F>(x)    /* swizzle xor 31 */
#define EX_F63(x) ((u32)__shfl_xor((int)(x), 63, 64))

// ---------------- Kernel 0: proj (k-major fp32) -> projT[p][k] bf16 ----------------
__global__ __launch_bounds__(256) void transpose_proj(const float* __restrict__ proj,
                                                      u16* __restrict__ projT) {
  const int k = blockIdx.x;
  const int p = threadIdx.x;
  projT[(size_t)p * 256 + k] = f2bf(proj[(size_t)k * 256 + p]);
}

// ---------------- Fused kernel: one block per graph --------------------------------
// Per block (1024 thr = 16 waves): x[g] (512x256 fp32) -> bf16 regs once.
// 4 p-quarters of 64 p: stage projT slice (XOR-swizzled LDS), MFMA (M=node, N=p),
// fp16 results -> LDS res[p_local][node], dual-packed bitonic sort per wave,
// in-place sorted park, block-wide quantile select + coalesced out writes.
__global__ __launch_bounds__(1024) void fused_swe(const float* __restrict__ x,
                                                  const u16* __restrict__ projT,
                                                  const float* __restrict__ cw,
                                                  float* __restrict__ out) {
  // LDS: [0, 32768)      Ps: 64 rows x 512 B (256 bf16), 16B segs XOR-swizzled
  //      [32768, 99328)  res: u32[64][260]  (row = p_local, 512 fp16 nodes + pad)
  extern __shared__ __attribute__((aligned(16))) char lds[];
  u32* res = (u32*)(lds + 32768);

  const int tid = threadIdx.x;
  const int lane = tid & 63;
  const int w = tid >> 6;        // wave 0..15
  const int g = blockIdx.x;      // graph
  const int quad = lane >> 4;    // 0..3
  const int m16 = lane & 15;

  // ---- load this wave's 2 node-16-tiles (rows g*512 + w*32 .. +32), all K, to regs
  bf16x8 a[2][8];
#pragma unroll
  for (int t = 0; t < 2; ++t) {
    const float* ap = x + (size_t)(g * 512 + w * 32 + t * 16 + m16) * 256 + quad * 8;
#pragma unroll
    for (int ks = 0; ks < 8; ++ks) {
      float4 f0 = *(const float4*)(ap + ks * 32);
      float4 f1 = *(const float4*)(ap + ks * 32 + 4);
      u32 pk4[4] = { cvtpk(f0.x, f0.y), cvtpk(f0.z, f0.w),
                     cvtpk(f1.x, f1.y), cvtpk(f1.z, f1.w) };
      a[t][ks] = *(const bf16x8*)pk4;
    }
  }

  for (int qtr = 0; qtr < 4; ++qtr) {
    // ---- P1: stage projT slice [64 p][256 k] bf16 with 16B-seg XOR swizzle
    // 64 rows x 32 segs of 16B = 32 KiB -> 1024 threads x 2 segs each.
    {
      const int row = tid >> 4;    // p_local 0..63
      const int seg0 = tid & 15;
#pragma unroll
      for (int si = 0; si < 2; ++si) {
        const int seg = seg0 + si * 16;  // 0..31: full 256-k row
        uint4 d = *(const uint4*)(projT + (size_t)(qtr * 64 + row) * 256 + seg * 8);
        *(uint4*)(lds + row * 512 + ((seg ^ (row & 7)) * 16)) = d;
      }
    }
    __syncthreads();

    // ---- P2: GEMM  C[node][p] ; A-frag from regs, B-frag from swizzled LDS
#pragma unroll
    for (int nt = 0; nt < 4; ++nt) {
      const int prow = nt * 16 + m16;
      const int rx = (prow & 7) << 4;
      const char* pb = lds + prow * 512;
      f32x4 acc0 = {0.f, 0.f, 0.f, 0.f};
      f32x4 acc1 = {0.f, 0.f, 0.f, 0.f};
#pragma unroll
      for (int ks = 0; ks < 8; ++ks) {
        bf16x8 bfrag = *(const bf16x8*)(pb + (((ks * 64) | (quad * 16)) ^ rx));
        acc0 = __builtin_amdgcn_mfma_f32_16x16x32_bf16(a[0][ks], bfrag, acc0, 0, 0, 0);
        acc1 = __builtin_amdgcn_mfma_f32_16x16x32_bf16(a[1][ks], bfrag, acc1, 0, 0, 0);
      }
      // C row = node = w*32 + t*16 + quad*4 + r ; col = p_local = prow
      const int wb = prow * 260 + w * 16 + quad * 2;
      res[wb]     = pkh(acc0[0], acc0[1]);
      res[wb + 1] = pkh(acc0[2], acc0[3]);
      res[wb + 8] = pkh(acc1[0], acc1[1]);
      res[wb + 9] = pkh(acc1[2], acc1[3]);
    }
    __syncthreads();

    // ---- P3/P4: dual-packed bitonic sort (columns d and d+32), in-place park
#pragma unroll
    for (int s = 0; s < 2; ++s) {
      const int d = w * 2 + s;
      u32* ra = res + d * 260;
      u32* rb = res + (d + 32) * 260;
      uint4 a4 = *(const uint4*)(ra + lane * 4);
      uint4 b4 = *(const uint4*)(rb + lane * 4);
      u32 v[8];
      v[0] = vperm(b4.x, a4.x, 0x05040100u); v[1] = vperm(b4.x, a4.x, 0x07060302u);
      v[2] = vperm(b4.y, a4.y, 0x05040100u); v[3] = vperm(b4.y, a4.y, 0x07060302u);
      v[4] = vperm(b4.z, a4.z, 0x05040100u); v[5] = vperm(b4.z, a4.z, 0x07060302u);
      v[6] = vperm(b4.w, a4.w, 0x05040100u); v[7] = vperm(b4.w, a4.w, 0x07060302u);

#define CE(i, j) { u32 mn_ = pkmin(v[i], v[j]); u32 mx_ = pkmax(v[i], v[j]); v[i] = mn_; v[j] = mx_; }
#define INTRA3 \
  CE(0,4) CE(1,5) CE(2,6) CE(3,7) \
  CE(0,2) CE(1,3) CE(4,6) CE(5,7) \
  CE(0,1) CE(2,3) CE(4,5) CE(6,7)

#define FLIPP(EX, lowbit) { \
    const bool low_ = (lane & (lowbit)) == 0; \
    u32 t_[8]; \
    _Pragma("unroll") for (int r = 0; r < 8; ++r) t_[r] = EX(v[7 - r]); \
    _Pragma("unroll") for (int r = 0; r < 8; ++r) { \
      u32 mn_ = pkmin(v[r], t_[r]); u32 mx_ = pkmax(v[r], t_[r]); \
      v[r] = low_ ? mn_ : mx_; } }

#define XCROSSP(EX, lm) { \
    const bool low_ = (lane & (lm)) == 0; \
    _Pragma("unroll") for (int r = 0; r < 8; ++r) { \
      u32 t_ = EX(v[r]); \
      u32 mn_ = pkmin(v[r], t_); u32 mx_ = pkmax(v[r], t_); \
      v[r] = low_ ? mn_ : mx_; } }

      // S=2
      CE(0,1) CE(2,3) CE(4,5) CE(6,7)
      // S=4
      CE(0,3) CE(1,2) CE(4,7) CE(5,6)
      CE(0,1) CE(2,3) CE(4,5) CE(6,7)
      // S=8
      CE(0,7) CE(1,6) CE(2,5) CE(3,4)
      CE(0,2) CE(1,3) CE(4,6) CE(5,7)
      CE(0,1) CE(2,3) CE(4,5) CE(6,7)
      // S=16
      FLIPP(EX_X1, 1)  INTRA3
      // S=32
      FLIPP(EX_F3, 2)  XCROSSP(EX_X1, 1)  INTRA3
      // S=64
      FLIPP(EX_F7, 4)  XCROSSP(EX_X2, 2) XCROSSP(EX_X1, 1)  INTRA3
      // S=128
      FLIPP(EX_F15, 8) XCROSSP(EX_X4, 4) XCROSSP(EX_X2, 2) XCROSSP(EX_X1, 1)  INTRA3
      // S=256
      FLIPP(EX_F31, 16) XCROSSP(EX_X8, 8) XCROSSP(EX_X4, 4) XCROSSP(EX_X2, 2) XCROSSP(EX_X1, 1)  INTRA3
      // S=512
      FLIPP(EX_F63, 32) XCROSSP(EX_X16, 16) XCROSSP(EX_X8, 8) XCROSSP(EX_X4, 4) XCROSSP(EX_X2, 2) XCROSSP(EX_X1, 1)  INTRA3

#undef CE
#undef INTRA3
#undef FLIPP
#undef XCROSSP

      // in-place park of sorted dual: index i = lane*8 + r ; i<256 -> row d, else d+32
      u32* pp = (lane < 32) ? (ra + lane * 8) : (rb + lane * 8 - 256);
      *(uint4*)pp       = (uint4){v[0], v[1], v[2], v[3]};
      *(uint4*)(pp + 4) = (uint4){v[4], v[5], v[6], v[7]};
    }
    __syncthreads();

    // ---- P5: quantile select + coalesced write (64 p-cols of this quarter)
#pragma unroll
    for (int it = 0; it < 16; ++it) {
      const int linear = it * 1024 + tid;  // 0..16383
      const int q = linear >> 6;           // wave-uniform
      const int pc = linear & 63;
      const int iq = (int)floorf(cw[q] * 511.0f);
      const int dd = pc & 31;
      const u32 val = res[dd * 260 + ((iq >= 256) ? (iq + 8064) : iq)];
      const u16 h = (pc & 32) ? (u16)(val >> 16) : (u16)(val & 0xFFFF);
      __half_raw hr; hr.x = h;
      out[(size_t)g * 65536 + (size_t)q * 256 + qtr * 64 + pc] =
          __half2float(__half(hr)) * 0.00390625f;
    }
    // next quarter: P1 touches Ps only; the sync after P1 orders P5 reads vs P2 writes
  }
}

extern "C" void kernel_launch(void* const* d_in, const int* in_sizes, int n_in,
                              void* d_out, int out_size, void* d_ws, size_t ws_size,
                              hipStream_t stream) {
  const float* x    = (const float*)d_in[0];  // (131072, 256) fp32
  const float* proj = (const float*)d_in[1];  // (256, 256) fp32
  const float* cw   = (const float*)d_in[2];  // (256,) fp32
  float* out = (float*)d_out;                 // (256, 65536) fp32

  u16* projT = (u16*)d_ws;                    // 128 KiB

  transpose_proj<<<256, 256, 0, stream>>>(proj, projT);
  fused_swe<<<256, 1024, 99328, stream>>>(x, projT, cw, out);
}